// Round 12
// baseline (8765.513 us; speedup 1.0000x reference)
//
#include <hip/hip_runtime.h>

// ---------------- problem dims ----------------
#define N_SEQ 64
#define T_LEN 512
#define IN_SZ 512
#define HID   1024
#define ODIM  256

// ---------------- config ----------------
#define REC_WGS  128
#define PROJ_WGS 16
#define TOT_WGS  (REC_WGS + PROJ_WGS)
#define BLK      256
#define RING_D   64                 // h ring depth (no addr reuse for 64 steps)
#define XD       4                  // LDS x-partial ring depth
#define HSLOT    (N_SEQ * HID)      // halves per h slot

// ws layout: int arr[2][128] @ 0 ; int arrp[64] @ 1024 B
#define HBUF_OFF 4096               // fp16 hb[64][64][1024] = 8 MiB

// ---------------- rec LDS layout (bytes, dynamic) ----------------
// frag-major weights: frags 0..31 = Wi (K 0..511), frags 32..95 = Wh (K 0..1023)
#define WF_OFF   0                  // 96 frags x 1024 B = 98304
#define CXR_OFF  98304              // f32 cxr[2][4][1088] = 34816 (x-partial ring)
#define GB_OFF   133120             // f32 gbuf[2][1056] = 8448
#define BIAS_OFF 141568             // f32[32] = 128
#define XFLG_OFF 141696             // int xflg[2], xcons[2]
#define LDS_BYTES 141824
// proj overlay
#define PWF_OFF 0                   // 32 frags x 1024 B
#define PB_OFF  32768               // f32[16]

typedef _Float16 half8  __attribute__((ext_vector_type(8)));
typedef float    f32x4  __attribute__((ext_vector_type(4)));
typedef float    f32x16 __attribute__((ext_vector_type(16)));

union U8B  { _Float16 h[4]; unsigned long long u; };

__device__ __forceinline__ float sigmf(float x) { return 1.f / (1.f + expf(-x)); }

__device__ __forceinline__ half8 cvt8(const float* p) {
  f32x4 v0 = *(const f32x4*)p;
  f32x4 v1 = *(const f32x4*)(p + 4);
  half8 h;
  h[0] = (_Float16)v0[0]; h[1] = (_Float16)v0[1];
  h[2] = (_Float16)v0[2]; h[3] = (_Float16)v0[3];
  h[4] = (_Float16)v1[0]; h[5] = (_Float16)v1[1];
  h[6] = (_Float16)v1[2]; h[7] = (_Float16)v1[3];
  return h;
}

#define ALOAD4(p) __hip_atomic_load((const int*)(p), __ATOMIC_RELAXED, __HIP_MEMORY_SCOPE_AGENT)
#define ASTORE8(p, v) __hip_atomic_store((unsigned long long*)(p), (v), __ATOMIC_RELAXED, __HIP_MEMORY_SCOPE_AGENT)

// poll one chain's 128 producer flags for >= tgt
#define POLL128(base_, tgt_) { for (;;) { \
    int m0_ = ALOAD4((base_) + lane); \
    int m1_ = ALOAD4((base_) + 64 + lane); \
    if (__all(min(m0_, m1_) >= (tgt_))) break; \
    __builtin_amdgcn_s_sleep(1); } \
  asm volatile("" ::: "memory"); }

// init: flags = -1, h0 -> ring slot RING_D-1
__global__ void init_kernel(const float* __restrict__ h0, unsigned char* __restrict__ ws) {
  int gid = blockIdx.x * 256 + threadIdx.x;
  if (gid < 320) ((int*)ws)[gid] = -1;
  _Float16* hlast = (_Float16*)(ws + HBUF_OFF) + (size_t)(RING_D - 1) * HSLOT;
  if (gid < N_SEQ * HID) hlast[gid] = (_Float16)h0[gid];
}

__launch_bounds__(BLK, 1)
__global__ void lstm_coop(const float* __restrict__ obs,
                          const float* __restrict__ c0,
                          const float* __restrict__ es,
                          const float* __restrict__ W_ih,
                          const float* __restrict__ W_hh,
                          const float* __restrict__ b_ih,
                          const float* __restrict__ b_hh,
                          const float* __restrict__ W_proj,
                          const float* __restrict__ b_proj,
                          float* __restrict__ out,
                          unsigned char* __restrict__ ws) {
  extern __shared__ char smem[];
  const int tid = threadIdx.x, bid = blockIdx.x;
  const int w = tid >> 6, lane = tid & 63;
  int* arr  = (int*)ws;           // [2][128] chain flags
  int* arrp = (int*)ws + 256;     // [64] proj lag flags
  _Float16* hb = (_Float16*)(ws + HBUF_OFF);

  if (bid < REC_WGS) {
    // ================= recurrent role =================
    const int wg = bid;
    _Float16* wf = (_Float16*)(smem + WF_OFF);
    float* cxr   = (float*)(smem + CXR_OFF);    // [2][4][1088], lane stride 17
    float* gbuf  = (float*)(smem + GB_OFF);     // [2][1056]
    float* bias  = (float*)(smem + BIAS_OFF);
    int*   xflg  = (int*)(smem + XFLG_OFF);     // [2]
    int*   xcons = (int*)(smem + XFLG_OFF) + 2; // [2]

    // stage Wi (frags 0..31) + Wh (frags 32..95) frag-major:
    // lane l holds B[col=l&31][k = fk*16 + (l>>5)*8 + j], 16 B contiguous.
    for (int idx = tid; idx < 96 * 64; idx += BLK) {
      int f = idx >> 6, l = idx & 63;
      int c = l & 31, kgl = (l >> 5) * 8;
      int grow = (c >> 3) * HID + wg * 8 + (c & 7);      // < 4096
      const float* src = (f < 32)
          ? (W_ih + (size_t)grow * IN_SZ + (f * 16 + kgl))
          : (W_hh + (size_t)grow * HID + ((f - 32) * 16 + kgl));
      _Float16* dst = wf + (size_t)idx * 8;
      #pragma unroll
      for (int j = 0; j < 8; ++j) dst[j] = (_Float16)src[j];
    }
    if (tid < 32) {
      int grow = (tid >> 3) * HID + wg * 8 + (tid & 7);
      bias[tid] = b_ih[grow] + b_hh[grow];
    }
    if (tid < 4) ((int*)(smem + XFLG_OFF))[tid] = -1;
    __syncthreads();

    const int ch = w & 1;          // sequence chain (32 seqs)
    const int role = w >> 1;       // 0 = main (h + combine + epilogue), 1 = x producer
    const int col = lane & 31, kg = (lane >> 5) * 8;
    const int n_a = ch * 32 + col;
    int* fl = arr + ch * 128;

    if (role == 0) {
      // ---------- main wave: poll -> h K=1024 -> +x partial -> epilogue ----------
      const int erow = lane >> 1, eq = lane & 1;
      const int n_e = ch * 32 + erow;
      const int hcb = wg * 8 + eq * 4;          // < 1024
      float cs[4];
      {
        f32x4 c4 = *(const f32x4*)(c0 + (size_t)n_e * HID + hcb);
        cs[0] = c4[0]; cs[1] = c4[1]; cs[2] = c4[2]; cs[3] = c4[3];
      }
      float* gb = gbuf + ch * 1056;

      for (int t = 0; t < T_LEN; ++t) {
        int ap = (t >= RING_D) ? ALOAD4(arrp + lane) : 0x7fffffff;
        float esv = es[(size_t)n_a * T_LEN + t];   // A-mask (prefetch)
        float m = 1.f - es[(size_t)n_e * T_LEN + t]; // epilogue mask (prefetch)
        bool kill = (esv != 0.f);

        if (t > 0) POLL128(fl, t - 1);

        // h part K=1024: frags 32..95, plain cached b128 loads (ring-evicted)
        const _Float16* hrr = hb + (size_t)((t + RING_D - 1) & (RING_D - 1)) * HSLOT +
                              (size_t)n_a * HID + kg;
        f32x16 acc = {};
        #pragma unroll
        for (int f = 0; f < 64; ++f) {
          half8 a = *(const half8*)(hrr + f * 16);
          if (kill) a = (half8){};
          half8 bv = *(const half8*)(wf + ((size_t)(32 + f) * 64 + lane) * 8);
          acc = __builtin_amdgcn_mfma_f32_32x32x16_f16(a, bv, acc, 0, 0, 0);
        }

        // x partial from LDS ring (producer runs ahead; usually no wait)
        while (__hip_atomic_load(&xflg[ch], __ATOMIC_ACQUIRE, __HIP_MEMORY_SCOPE_WORKGROUP) < t)
          __builtin_amdgcn_s_sleep(0);
        const float* cbc = cxr + ((ch * 4 + (t & 3)) * 1088) + lane * 17;
        float tot[16];
        #pragma unroll
        for (int r = 0; r < 16; ++r) tot[r] = acc[r] + cbc[r];
        if (lane == 0)
          __hip_atomic_store(&xcons[ch], t, __ATOMIC_RELEASE, __HIP_MEMORY_SCOPE_WORKGROUP);

        // transpose via gbuf (C/D m74: col=lane&31, row=(reg&3)+8*(reg>>2)+4*(lane>>5))
        #pragma unroll
        for (int reg = 0; reg < 16; ++reg) {
          int r = (reg & 3) + 8 * (reg >> 2) + 4 * (lane >> 5);
          gb[r * 33 + col] = tot[reg];
        }
        asm volatile("s_waitcnt lgkmcnt(0)" ::: "memory");

        // epilogue: 32 rows x 8 h-cols over 64 lanes
        U8B pk;
        #pragma unroll
        for (int p = 0; p < 4; ++p) {
          int j = eq * 4 + p;
          float pi = gb[erow * 33 + j]      + bias[j];
          float pf = gb[erow * 33 + 8 + j]  + bias[8 + j];
          float pg = gb[erow * 33 + 16 + j] + bias[16 + j];
          float po = gb[erow * 33 + 24 + j] + bias[24 + j];
          float cv = sigmf(pf) * (cs[p] * m) + sigmf(pi) * tanhf(pg);
          cs[p] = cv;
          pk.h[p] = (_Float16)(sigmf(po) * tanhf(cv));
        }

        // ring-reuse guard vs projection (rarely blocks)
        if (t >= RING_D) {
          while (!__all(ap >= t - RING_D)) {
            __builtin_amdgcn_s_sleep(2);
            ap = ALOAD4(arrp + lane);
          }
        }

        // publish h (sc1), ack, then flag
        ASTORE8(hb + (size_t)(t & (RING_D - 1)) * HSLOT + (size_t)n_e * HID + hcb, pk.u);
        asm volatile("s_waitcnt vmcnt(0)" ::: "memory");
        if (lane == 0)
          __hip_atomic_store(fl + wg, t, __ATOMIC_RELAXED, __HIP_MEMORY_SCOPE_AGENT);
      }
    } else {
      // ---------- x producer wave: gx(t) = x(t) @ Wi, runs ahead into LDS ring ----------
      for (int t = 0; t < T_LEN; ++t) {
        if (t >= XD) {
          while (__hip_atomic_load(&xcons[ch], __ATOMIC_ACQUIRE,
                                   __HIP_MEMORY_SCOPE_WORKGROUP) < t - XD)
            __builtin_amdgcn_s_sleep(1);
        }
        const float* xr = obs + ((size_t)n_a * T_LEN + t) * IN_SZ + kg;
        f32x16 acc = {};
        #pragma unroll
        for (int f = 0; f < 32; ++f) {
          half8 a = cvt8(xr + f * 16);
          half8 bv = *(const half8*)(wf + ((size_t)f * 64 + lane) * 8);
          acc = __builtin_amdgcn_mfma_f32_32x32x16_f16(a, bv, acc, 0, 0, 0);
        }
        float* cbw = cxr + ((ch * 4 + (t & 3)) * 1088) + lane * 17;
        *(f32x4*)(cbw + 0)  = (f32x4){acc[0],  acc[1],  acc[2],  acc[3]};
        *(f32x4*)(cbw + 4)  = (f32x4){acc[4],  acc[5],  acc[6],  acc[7]};
        *(f32x4*)(cbw + 8)  = (f32x4){acc[8],  acc[9],  acc[10], acc[11]};
        *(f32x4*)(cbw + 12) = (f32x4){acc[12], acc[13], acc[14], acc[15]};
        asm volatile("s_waitcnt lgkmcnt(0)" ::: "memory");
        if (lane == 0)
          __hip_atomic_store(&xflg[ch], t, __ATOMIC_RELEASE, __HIP_MEMORY_SCOPE_WORKGROUP);
      }
    }
  } else {
    // ================= projection role =================
    const int p = bid - REC_WGS;
    const int pbase = p * 16;
    _Float16* pwf = (_Float16*)(smem + PWF_OFF);
    float* pb = (float*)(smem + PB_OFF);
    for (int idx = tid; idx < 2048; idx += BLK) {
      int f = idx >> 6, l = idx & 63;
      int colp = pbase + (l & 15);
      int k0 = f * 32 + (l >> 4) * 8;
      _Float16* dst = pwf + (size_t)idx * 8;
      #pragma unroll
      for (int j = 0; j < 8; ++j)
        dst[j] = (_Float16)W_proj[(size_t)(k0 + j) * ODIM + colp];
    }
    if (tid < 16) pb[tid] = b_proj[pbase + tid];
    __syncthreads();

    const int rq = w;                 // row-quarter 0..3
    const int ch = rq >> 1;
    const int n0 = rq * 16;
    const int arow = n0 + (lane & 15);
    const int kg8p = (lane >> 4) * 8;
    const float bz = pb[lane & 15];
    int* fl = arr + ch * 128;

    for (int t = 0; t < T_LEN; ++t) {
      POLL128(fl, t);

      const _Float16* hr = hb + (size_t)(t & (RING_D - 1)) * HSLOT +
                           (size_t)arow * HID + kg8p;
      f32x4 acc = {};
      #pragma unroll
      for (int i = 0; i < 32; ++i) {
        half8 a = *(const half8*)(hr + i * 32);
        half8 bv = *(const half8*)(pwf + ((size_t)i * 64 + lane) * 8);
        acc = __builtin_amdgcn_mfma_f32_16x16x32_f16(a, bv, acc, 0, 0, 0);
      }
      #pragma unroll
      for (int r = 0; r < 4; ++r) {
        int nn = n0 + (lane >> 4) * 4 + r;
        out[((size_t)nn * T_LEN + t) * ODIM + pbase + (lane & 15)] = acc[r] + bz;
      }
      if (lane == 0)
        __hip_atomic_store(&arrp[p * 4 + w], t, __ATOMIC_RELAXED, __HIP_MEMORY_SCOPE_AGENT);
    }
  }
}

extern "C" void kernel_launch(void* const* d_in, const int* in_sizes, int n_in,
                              void* d_out, int out_size, void* d_ws, size_t ws_size,
                              hipStream_t stream) {
  const float* obs    = (const float*)d_in[0];
  const float* h0     = (const float*)d_in[1];
  const float* c0     = (const float*)d_in[2];
  const float* es     = (const float*)d_in[3];
  const float* W_ih   = (const float*)d_in[4];
  const float* W_hh   = (const float*)d_in[5];
  const float* b_ih   = (const float*)d_in[6];
  const float* b_hh   = (const float*)d_in[7];
  const float* W_proj = (const float*)d_in[8];
  const float* b_proj = (const float*)d_in[9];
  float* out = (float*)d_out;
  unsigned char* ws = (unsigned char*)d_ws;

  hipLaunchKernelGGL(init_kernel, dim3(256), dim3(256), 0, stream, h0, ws);

  hipFuncSetAttribute((const void*)lstm_coop,
                      hipFuncAttributeMaxDynamicSharedMemorySize, LDS_BYTES);

  void* args[] = { (void*)&obs, (void*)&c0, (void*)&es, (void*)&W_ih, (void*)&W_hh,
                   (void*)&b_ih, (void*)&b_hh, (void*)&W_proj, (void*)&b_proj,
                   (void*)&out, (void*)&ws };
  hipLaunchCooperativeKernel((const void*)lstm_coop, dim3(TOT_WGS), dim3(BLK),
                             args, LDS_BYTES, stream);
}